// Round 4
// baseline (1353.761 us; speedup 1.0000x reference)
//
#include <hip/hip_runtime.h>
#include <hip/hip_bf16.h>

#define BB 4
#define SS 1024
#define HID 1024
#define NH 16
#define NKV 4
#define DH 64
#define NREP 4
#define QLD 1536  // fused qkv row stride (cols: q 0..1023, k 1024..1279, v 1280..1535)

typedef __hip_bfloat16 bf16;
typedef __bf16 bf16x8 __attribute__((ext_vector_type(8)));
typedef float f32x4 __attribute__((ext_vector_type(4)));
typedef unsigned short us8 __attribute__((ext_vector_type(8)));
typedef unsigned short us4 __attribute__((ext_vector_type(4)));

__device__ inline unsigned short f2b(float f) {
  union { bf16 b; unsigned short u; } x;
  x.b = __float2bfloat16(f);
  return x.u;
}
__device__ inline float b2f(unsigned short u) {
  union { unsigned int i; float f; } x;
  x.i = ((unsigned int)u) << 16;
  return x.f;
}
__device__ inline float blo(unsigned int u) {
  union { unsigned int i; float f; } x;
  x.i = u << 16;
  return x.f;
}
__device__ inline float bhi(unsigned int u) {
  union { unsigned int i; float f; } x;
  x.i = u & 0xffff0000u;
  return x.f;
}

// ---------------------------------------------------------------------------
// fp32 -> bf16 elementwise (4 elems/thread)
// ---------------------------------------------------------------------------
__global__ __launch_bounds__(256) void convert_bf16(const float* __restrict__ in,
                                                    unsigned short* __restrict__ out,
                                                    int n) {
  int i = (blockIdx.x * 256 + threadIdx.x) * 4;
  if (i >= n) return;
  float4 v = *(const float4*)(in + i);
  us4 o = {f2b(v.x), f2b(v.y), f2b(v.z), f2b(v.w)};
  *(us4*)(out + i) = o;
}

// ---------------------------------------------------------------------------
// W [1024][N] fp32 -> WT [N][1024] bf16 (LDS 64x64 tile transpose)
// ---------------------------------------------------------------------------
__global__ __launch_bounds__(256) void wtrans(const float* __restrict__ W,
                                              unsigned short* __restrict__ WT,
                                              int N) {
  __shared__ float tile[64][65];
  const int t = threadIdx.x;
  const int nb = blockIdx.x;  // col tile of W
  const int kb = blockIdx.y;  // row tile of W
#pragma unroll
  for (int p = 0; p < 16; p++) {
    int kl = p * 4 + (t >> 6);
    int nl = t & 63;
    tile[kl][nl] = W[(size_t)(kb * 64 + kl) * N + nb * 64 + nl];
  }
  __syncthreads();
#pragma unroll
  for (int p = 0; p < 16; p++) {
    int nl = p * 4 + (t >> 6);
    int kl = t & 63;
    WT[(size_t)(nb * 64 + nl) * 1024 + kb * 64 + kl] = f2b(tile[kl][nl]);
  }
}

// ---------------------------------------------------------------------------
// MFMA GEMM: C[M,N] = A[M,K] @ BT[N,K]^T. bf16 inputs, fp32 accumulate.
// 128x128 tile, BK=32, 256 threads (4 waves, 2x2 of 64x64), m97 structure.
// ---------------------------------------------------------------------------
template <bool OUT_BF16>
__global__ __launch_bounds__(256) void gemm_bt_mfma(
    const unsigned short* __restrict__ A,   // [M][K] bf16
    const unsigned short* __restrict__ BT,  // [N][K] bf16
    void* __restrict__ Cv, int M, int N, int K) {
  __shared__ __attribute__((aligned(16))) unsigned short Atile[128 * 32];
  __shared__ __attribute__((aligned(16))) unsigned short Btile[128 * 32];
  const int t = threadIdx.x;
  const int w = t >> 6;
  const int lane = t & 63;
  const int wm = w >> 1, wn = w & 1;
  const int q = lane >> 4;    // quad 0..3
  const int l16 = lane & 15;
  const int rowBase = blockIdx.y * 128;
  const int colBase = blockIdx.x * 128;

  f32x4 acc[4][4] = {};

  for (int k0 = 0; k0 < K; k0 += 32) {
#pragma unroll
    for (int j = 0; j < 2; j++) {
      int r = w * 32 + j * 16 + (lane >> 2);
      int ce = (lane & 3) * 8;  // element offset, 8 bf16 = 16 B
      const unsigned short* ga = A + (size_t)(rowBase + r) * K + k0 + ce;
      const unsigned short* gb = BT + (size_t)(colBase + r) * K + k0 + ce;
      __builtin_amdgcn_global_load_lds(
          (__attribute__((address_space(1))) void*)ga,
          (__attribute__((address_space(3))) void*)&Atile[(w * 32 + j * 16) * 32],
          16, 0, 0);
      __builtin_amdgcn_global_load_lds(
          (__attribute__((address_space(1))) void*)gb,
          (__attribute__((address_space(3))) void*)&Btile[(w * 32 + j * 16) * 32],
          16, 0, 0);
    }
    asm volatile("s_waitcnt vmcnt(0)" ::: "memory");
    __syncthreads();

    bf16x8 af[4], bfv[4];
#pragma unroll
    for (int mi = 0; mi < 4; mi++) {
      int m = wm * 64 + mi * 16 + l16;
      af[mi] = __builtin_bit_cast(bf16x8, *(const us8*)&Atile[m * 32 + q * 8]);
    }
#pragma unroll
    for (int ni = 0; ni < 4; ni++) {
      int n = wn * 64 + ni * 16 + l16;
      bfv[ni] = __builtin_bit_cast(bf16x8, *(const us8*)&Btile[n * 32 + q * 8]);
    }
#pragma unroll
    for (int mi = 0; mi < 4; mi++)
#pragma unroll
      for (int ni = 0; ni < 4; ni++)
        acc[mi][ni] = __builtin_amdgcn_mfma_f32_16x16x32_bf16(
            af[mi], bfv[ni], acc[mi][ni], 0, 0, 0);
    __syncthreads();
  }

#pragma unroll
  for (int mi = 0; mi < 4; mi++)
#pragma unroll
    for (int ni = 0; ni < 4; ni++)
#pragma unroll
      for (int r = 0; r < 4; r++) {
        int row = rowBase + wm * 64 + mi * 16 + q * 4 + r;
        int col = colBase + wn * 64 + ni * 16 + l16;
        float v = acc[mi][ni][r];
        if (OUT_BF16)
          ((unsigned short*)Cv)[(size_t)row * N + col] = f2b(v);
        else
          ((float*)Cv)[(size_t)row * N + col] = v;
      }
}

// ---------------------------------------------------------------------------
// Attention: one block per (q-row, kv-head, batch); 4 query heads per block.
// qkv fused bf16 [B*S][1536]; bias fp32; math fp32.
// ---------------------------------------------------------------------------
__global__ __launch_bounds__(256) void attn_kernel(
    const unsigned short* __restrict__ qkv,  // [B*S][QLD] bf16
    const float* __restrict__ bias,          // [B, NH, S, S]
    const int* __restrict__ mask,            // [B, 1, S, S]
    unsigned short* __restrict__ attn)       // [B*S][NH*DH] bf16
{
  const int sq = blockIdx.x;
  const int kvh = blockIdx.y;
  const int b = blockIdx.z;

  __shared__ float qs[NREP][DH];
  __shared__ float sc[NREP][SS];
  __shared__ float part[4][NREP][DH];

  const int t = threadIdx.x;

  ((float*)qs)[t] = b2f(qkv[(size_t)(b * SS + sq) * QLD + kvh * NREP * DH + t]);
  __syncthreads();

  // ---- phase 1: scores = q.kT/8 + bias, masked ----
  const unsigned short* kb = qkv + (size_t)b * SS * QLD + 1024 + kvh * DH;
  const int* mrow = mask + ((size_t)b * SS + sq) * SS;
  const float* brow = bias + (((size_t)b * NH + kvh * NREP) * SS + sq) * SS;

#pragma unroll
  for (int i = 0; i < 4; i++) {
    int kk = t + i * 256;
    const uint4* krow = (const uint4*)(kb + (size_t)kk * QLD);
    float dd[NREP] = {0.f, 0.f, 0.f, 0.f};
#pragma unroll
    for (int dv = 0; dv < DH / 8; dv++) {
      uint4 kx = krow[dv];
      float kf[8];
      kf[0] = blo(kx.x); kf[1] = bhi(kx.x);
      kf[2] = blo(kx.y); kf[3] = bhi(kx.y);
      kf[4] = blo(kx.z); kf[5] = bhi(kx.z);
      kf[6] = blo(kx.w); kf[7] = bhi(kx.w);
#pragma unroll
      for (int r = 0; r < NREP; r++) {
#pragma unroll
        for (int j = 0; j < 8; j++) dd[r] += qs[r][dv * 8 + j] * kf[j];
      }
    }
    bool live = mrow[kk] != 0;
#pragma unroll
    for (int r = 0; r < NREP; r++) {
      float val = dd[r] * 0.125f + brow[(size_t)r * SS * SS + kk];
      sc[r][kk] = live ? val : -1e9f;
    }
  }
  __syncthreads();

  // ---- phase 2: softmax, one wave per head-row ----
  {
    const int wave = t >> 6;
    const int lane = t & 63;
    float mx = -1e30f;
    for (int i = lane; i < SS; i += 64) mx = fmaxf(mx, sc[wave][i]);
#pragma unroll
    for (int off = 32; off; off >>= 1) mx = fmaxf(mx, __shfl_xor(mx, off));
    float sum = 0.f;
    for (int i = lane; i < SS; i += 64) {
      float e = __expf(sc[wave][i] - mx);
      sc[wave][i] = e;
      sum += e;
    }
#pragma unroll
    for (int off = 32; off; off >>= 1) sum += __shfl_xor(sum, off);
    float inv = 1.0f / sum;
    for (int i = lane; i < SS; i += 64) sc[wave][i] *= inv;
  }
  __syncthreads();

  // ---- phase 3: out = w @ V ----
  {
    const int d = t & 63;
    const int c = t >> 6;
    const unsigned short* vb = qkv + (size_t)b * SS * QLD + 1280 + kvh * DH + d;
    float o[NREP] = {0.f, 0.f, 0.f, 0.f};
    for (int kk = c * 256; kk < c * 256 + 256; kk++) {
      float vv = b2f(vb[(size_t)kk * QLD]);
#pragma unroll
      for (int r = 0; r < NREP; r++) o[r] += sc[r][kk] * vv;
    }
#pragma unroll
    for (int r = 0; r < NREP; r++) part[c][r][d] = o[r];
    __syncthreads();
    if (c == 0) {
#pragma unroll
      for (int r = 0; r < NREP; r++) {
        float s = part[0][r][d] + part[1][r][d] + part[2][r][d] + part[3][r][d];
        attn[(size_t)(b * SS + sq) * (NH * DH) + (kvh * NREP + r) * DH + d] =
            f2b(s);
      }
    }
  }
}

// ---------------------------------------------------------------------------
extern "C" void kernel_launch(void* const* d_in, const int* in_sizes, int n_in,
                              void* d_out, int out_size, void* d_ws,
                              size_t ws_size, hipStream_t stream) {
  const float* hs = (const float*)d_in[0];    // [B,S,HID]
  const float* bias = (const float*)d_in[1];  // [B,NH,S,S]
  const int* mask = (const int*)d_in[2];      // [B,1,S,S]
  const float* Wq = (const float*)d_in[3];    // [HID, 1024]
  const float* Wk = (const float*)d_in[4];    // [HID, 256]
  const float* Wv = (const float*)d_in[5];    // [HID, 256]
  const float* Wo = (const float*)d_in[6];    // [HID, HID]
  float* out = (float*)d_out;                 // [B,S,HID] fp32

  const int M = BB * SS;  // 4096
  char* ws = (char*)d_ws;
  // layout: [hsb/at 8MB][qkv 12MB][WqkvT 3MB][WoT 2MB] = 25 MB
  unsigned short* hsb = (unsigned short*)ws;                  // [4096][1024]
  unsigned short* at = hsb;                                   // aliased (hsb dead after QKV gemm)
  unsigned short* qkvb = (unsigned short*)(ws + (8u << 20));  // [4096][1536]
  unsigned short* WqkvT = (unsigned short*)(ws + (20u << 20)); // [1536][1024]
  unsigned short* WoT = (unsigned short*)(ws + (23u << 20));   // [1024][1024]

  // converts / transposes
  convert_bf16<<<dim3(M * HID / 1024), 256, 0, stream>>>(hs, hsb, M * HID);
  wtrans<<<dim3(16, 16), 256, 0, stream>>>(Wq, WqkvT, 1024);
  wtrans<<<dim3(4, 16), 256, 0, stream>>>(Wk, WqkvT + (size_t)1024 * 1024, 256);
  wtrans<<<dim3(4, 16), 256, 0, stream>>>(Wv, WqkvT + (size_t)1280 * 1024, 256);
  wtrans<<<dim3(16, 16), 256, 0, stream>>>(Wo, WoT, 1024);

  // fused QKV projection: [4096][1024] x [1536][1024]^T -> [4096][1536] bf16
  gemm_bt_mfma<true>
      <<<dim3(QLD / 128, M / 128), 256, 0, stream>>>(hsb, WqkvT, qkvb, M, QLD, HID);

  attn_kernel<<<dim3(SS, NKV, BB), 256, 0, stream>>>(qkvb, bias, mask, at);

  // output projection: [4096][1024] x [1024][1024]^T -> fp32 out
  gemm_bt_mfma<false>
      <<<dim3(HID / 128, M / 128), 256, 0, stream>>>(at, WoT, out, M, HID, HID);
}